// Round 8
// baseline (705.862 us; speedup 1.0000x reference)
//
#include <hip/hip_runtime.h>
#include <float.h>

// Problem constants (from reference file)
constexpr int C    = 512;          // DIM_CODES
constexpr int K    = 512;          // DICT_SIZE
constexpr int E    = 16;           // EMBED_DIM
constexpr int B    = 512;          // BATCH
constexpr int MUS  = C * E;        // 8192, mu row stride
constexpr int R    = 4;            // query rows per lane

// ============================================================================
// Kernel 0 — zero the one-hot buffer. EXACT fill-kernel pattern: grid-stride
// plain float4 stores, no reads, no VALU, no nt-hint, no data dependence.
// The harness's own fill proves this shape runs at ~6.26 TB/s on this chip.
// The 512 MB one-hot payload then never depends on the argmin result: the
// scan only scatters B*C single 1.0f stores on top (0.5% of the bytes).
// ============================================================================
__launch_bounds__(256)
__global__ void vq_zero(float4* __restrict__ oh4)
{
    const int TOT    = B * C * K / 4;              // 33,554,432 float4s
    const int stride = gridDim.x * blockDim.x;
    for (int i = blockIdx.x * blockDim.x + threadIdx.x; i < TOT; i += stride)
        oh4[i] = make_float4(0.f, 0.f, 0.f, 0.f);
}

// ============================================================================
// Kernel 1 — argmin scan. Hot loop and numerics BYTE-IDENTICAL to v7 (the
// 669.8us verified best): R=4 rows per lane, one dict LDS broadcast per k
// feeds 4 fma chains; per-lane strict-< argmin (first-index ties); rare
// near-ties (sec < bd + 1e-3) resolved by the wave-cooperative fp64 re-scan.
// Only the epilogue changed: instead of idx_t, scatter oh[...]=1.0f directly
// (zero kernel ran first on the stream) and keep z/zq register writes.
// ============================================================================
__launch_bounds__(128, 1)
__global__ void vq_scan(const float* __restrict__ mu,
                        const float* __restrict__ dict,
                        float* __restrict__ z,
                        float* __restrict__ zq,
                        float* __restrict__ oh)
{
    const int c    = blockIdx.x;
    const int tid  = threadIdx.x;
    const int lane = tid & 63;
    const int wave = tid >> 6;

    __shared__ __align__(16) float dict_s[K * E];   // 32 KB
    __shared__ float nrm_s[K];                      // 2 KB

    const float* __restrict__ dbase = dict + (size_t)c * K * E;

    // ---- stage dict slice + per-code squared norms (verified fma order)
#pragma unroll
    for (int rep = 0; rep < 4; ++rep) {
        const int k = tid + rep * 128;
        const float4* p = reinterpret_cast<const float4*>(dbase + k * E);
        const float4 d0 = p[0], d1 = p[1], d2 = p[2], d3 = p[3];
        float s = d0.x * d0.x;
        s = fmaf(d0.y, d0.y, s); s = fmaf(d0.z, d0.z, s); s = fmaf(d0.w, d0.w, s);
        s = fmaf(d1.x, d1.x, s); s = fmaf(d1.y, d1.y, s);
        s = fmaf(d1.z, d1.z, s); s = fmaf(d1.w, d1.w, s);
        s = fmaf(d2.x, d2.x, s); s = fmaf(d2.y, d2.y, s);
        s = fmaf(d2.z, d2.z, s); s = fmaf(d2.w, d2.w, s);
        s = fmaf(d3.x, d3.x, s); s = fmaf(d3.y, d3.y, s);
        s = fmaf(d3.z, d3.z, s); s = fmaf(d3.w, d3.w, s);
        float4* q4 = reinterpret_cast<float4*>(&dict_s[k * E]);
        q4[0] = d0; q4[1] = d1; q4[2] = d2; q4[3] = d3;
        nrm_s[k] = s;
    }
    __syncthreads();

    // ---- this lane's R query rows: row = tid + 128*s  (covers B=512)
    float4 m[R][4];
    float  nm[R];
#pragma unroll
    for (int s = 0; s < R; ++s) {
        const int b = tid + 128 * s;
        const float4* p = reinterpret_cast<const float4*>(
            mu + (size_t)b * MUS + c * E);
        m[s][0] = p[0]; m[s][1] = p[1]; m[s][2] = p[2]; m[s][3] = p[3];
        float v = m[s][0].x * m[s][0].x;
        v = fmaf(m[s][0].y, m[s][0].y, v);
        v = fmaf(m[s][0].z, m[s][0].z, v);
        v = fmaf(m[s][0].w, m[s][0].w, v);
#pragma unroll
        for (int t = 1; t < 4; ++t) {
            v = fmaf(m[s][t].x, m[s][t].x, v);
            v = fmaf(m[s][t].y, m[s][t].y, v);
            v = fmaf(m[s][t].z, m[s][t].z, v);
            v = fmaf(m[s][t].w, m[s][t].w, v);
        }
        nm[s] = v;
    }

    // ---- serial scan over all K codes; ONE dict broadcast feeds R rows.
    float bd[R], sec[R];
    int   bk[R];
#pragma unroll
    for (int s = 0; s < R; ++s) { bd[s] = FLT_MAX; sec[s] = FLT_MAX; bk[s] = K; }

    const float4* __restrict__ ds4 = reinterpret_cast<const float4*>(dict_s);
#pragma unroll 4
    for (int k = 0; k < K; ++k) {
        const float4 d0 = ds4[k * 4 + 0];
        const float4 d1 = ds4[k * 4 + 1];
        const float4 d2 = ds4[k * 4 + 2];
        const float4 d3 = ds4[k * 4 + 3];
        const float  nr = nrm_s[k];
#pragma unroll
        for (int s = 0; s < R; ++s) {
            float acc = d0.x * m[s][0].x;
            acc = fmaf(d0.y, m[s][0].y, acc);
            acc = fmaf(d0.z, m[s][0].z, acc);
            acc = fmaf(d0.w, m[s][0].w, acc);
            acc = fmaf(d1.x, m[s][1].x, acc);
            acc = fmaf(d1.y, m[s][1].y, acc);
            acc = fmaf(d1.z, m[s][1].z, acc);
            acc = fmaf(d1.w, m[s][1].w, acc);
            acc = fmaf(d2.x, m[s][2].x, acc);
            acc = fmaf(d2.y, m[s][2].y, acc);
            acc = fmaf(d2.z, m[s][2].z, acc);
            acc = fmaf(d2.w, m[s][2].w, acc);
            acc = fmaf(d3.x, m[s][3].x, acc);
            acc = fmaf(d3.y, m[s][3].y, acc);
            acc = fmaf(d3.z, m[s][3].z, acc);
            acc = fmaf(d3.w, m[s][3].w, acc);
            // identical rounding to the verified kernel
            const float dist = fmaf(-2.0f, acc, nm[s] + nr);
            const bool  lt   = dist < bd[s];         // ascending k =>
            sec[s] = lt ? bd[s] : fminf(sec[s], dist);  // first-index ties
            bd[s]  = lt ? dist : bd[s];
            bk[s]  = lt ? k : bk[s];
        }
    }

    // ---- rare near-tie path: wave-cooperative fp64 re-scan per flagged row.
#pragma unroll
    for (int s = 0; s < R; ++s) {
        unsigned long long trig = __ballot(sec[s] < bd[s] + 1e-3f);
        while (trig) {
            const int r = __ffsll(trig) - 1;
            trig &= trig - 1;
            const int row = (wave << 6) + r + 128 * s;
            const float* __restrict__ qrow = mu + (size_t)row * MUS + c * E;

            double nmuD = 0.0;
#pragma unroll
            for (int t = 0; t < E; ++t) {
                const double mt = (double)qrow[t];
                nmuD += mt * mt;
            }
            double bD = DBL_MAX;
            int    bK = K;
#pragma unroll
            for (int i = 0; i < 8; ++i) {
                const int kk = lane + 64 * i;
                const float* dk = &dict_s[kk * E];
                double nd = 0.0, dt = 0.0;
#pragma unroll
                for (int t = 0; t < 4; ++t) {
                    const double dx = dk[4 * t + 0], dy = dk[4 * t + 1];
                    const double dz = dk[4 * t + 2], dw = dk[4 * t + 3];
                    const double mx = qrow[4 * t + 0], my = qrow[4 * t + 1];
                    const double mz = qrow[4 * t + 2], mw = qrow[4 * t + 3];
                    nd += dx * dx + dy * dy + dz * dz + dw * dw;
                    dt += dx * mx + dy * my + dz * mz + dw * mw;
                }
                const double dist = nmuD + nd - 2.0 * dt;
                if (dist < bD) { bD = dist; bK = kk; }
            }
#pragma unroll
            for (int off = 32; off; off >>= 1) {
                const double od = __shfl_down(bD, off);
                const int    ok = __shfl_down(bK, off);
                if (od < bD || (od == bD && ok < bK)) { bD = od; bK = ok; }
            }
            const int kwin = __shfl(bK, 0);
            if (lane == r) bk[s] = kwin;
        }
    }

    // ---- outputs per slot: one-hot scatter (buffer pre-zeroed), z/zq.
#pragma unroll
    for (int s = 0; s < R; ++s) {
        const int b = tid + 128 * s;

        oh[((size_t)b * C + c) * K + bk[s]] = 1.0f;

        const float4* dwin = reinterpret_cast<const float4*>(&dict_s[bk[s] * E]);
        const float4 q0 = dwin[0], q1 = dwin[1], q2 = dwin[2], q3 = dwin[3];
        float* zqp = zq + (size_t)b * MUS + (size_t)c * E;
        float* zp  = z  + (size_t)b * MUS + (size_t)c * E;
        reinterpret_cast<float4*>(zqp)[0] = q0;
        reinterpret_cast<float4*>(zqp)[1] = q1;
        reinterpret_cast<float4*>(zqp)[2] = q2;
        reinterpret_cast<float4*>(zqp)[3] = q3;
        float4 z0, z1, z2, z3;
        z0.x = m[s][0].x + (q0.x - m[s][0].x); z0.y = m[s][0].y + (q0.y - m[s][0].y);
        z0.z = m[s][0].z + (q0.z - m[s][0].z); z0.w = m[s][0].w + (q0.w - m[s][0].w);
        z1.x = m[s][1].x + (q1.x - m[s][1].x); z1.y = m[s][1].y + (q1.y - m[s][1].y);
        z1.z = m[s][1].z + (q1.z - m[s][1].z); z1.w = m[s][1].w + (q1.w - m[s][1].w);
        z2.x = m[s][2].x + (q2.x - m[s][2].x); z2.y = m[s][2].y + (q2.y - m[s][2].y);
        z2.z = m[s][2].z + (q2.z - m[s][2].z); z2.w = m[s][2].w + (q2.w - m[s][2].w);
        z3.x = m[s][3].x + (q3.x - m[s][3].x); z3.y = m[s][3].y + (q3.y - m[s][3].y);
        z3.z = m[s][3].z + (q3.z - m[s][3].z); z3.w = m[s][3].w + (q3.w - m[s][3].w);
        reinterpret_cast<float4*>(zp)[0] = z0;
        reinterpret_cast<float4*>(zp)[1] = z1;
        reinterpret_cast<float4*>(zp)[2] = z2;
        reinterpret_cast<float4*>(zp)[3] = z3;
    }
}

extern "C" void kernel_launch(void* const* d_in, const int* in_sizes, int n_in,
                              void* d_out, int out_size, void* d_ws, size_t ws_size,
                              hipStream_t stream)
{
    const float* mu   = (const float*)d_in[0];
    const float* dict = (const float*)d_in[1];

    float* z  = (float*)d_out;                 // (B, C*E)
    float* zq = z  + (size_t)B * C * E;        // (B, C*E)
    float* oh = zq + (size_t)B * C * E;        // (B, C, K)

    vq_zero<<<2048, 256, 0, stream>>>(reinterpret_cast<float4*>(oh));
    vq_scan<<<dim3(C), 128, 0, stream>>>(mu, dict, z, zq, oh);
}

// Round 9
// 670.449 us; speedup vs baseline: 1.0528x; 1.0528x over previous
//
#include <hip/hip_runtime.h>
#include <float.h>

// Problem constants (from reference file)
constexpr int C    = 512;          // DIM_CODES
constexpr int K    = 512;          // DICT_SIZE
constexpr int E    = 16;           // EMBED_DIM
constexpr int B    = 512;          // BATCH
constexpr int MUS  = C * E;        // 8192, mu row stride
constexpr int R    = 4;            // query rows per lane

// native vector type for nontemporal 16B stores
typedef float f32x4 __attribute__((ext_vector_type(4)));

// ============================================================================
// Kernel 1 — argmin scan. v9 = v7 (669.8us best) + explicit 2-stage register
// double-buffer on the dict LDS broadcast.
// v4/v5/v7 scaling law: scan time tracks ONLY k-iterations-per-wave
// (~1050-1200 cyc/iter, invariant to waves/SIMD and per-iter VALU work) =>
// each iteration carries ~1000 cyc of un-pipelined LDS latency across the
// loop backedge. Fix: issue k+1's 5 LDS reads into named buffer B, compute
// k from buffer A under them (70 fma), alternate. Pad row K removes the
// tail branch. Everything else byte-identical to v7.
// ============================================================================
__launch_bounds__(128, 1)
__global__ void vq_scan(const float* __restrict__ mu,
                        const float* __restrict__ dict,
                        float* __restrict__ z,
                        float* __restrict__ zq,
                        int*   __restrict__ idx_t)
{
    const int c    = blockIdx.x;
    const int tid  = threadIdx.x;
    const int lane = tid & 63;
    const int wave = tid >> 6;

    __shared__ __align__(16) float dict_s[(K + 1) * E];  // 32 KB + pad row
    __shared__ float nrm_s[K + 1];                       // 2 KB + pad

    const float* __restrict__ dbase = dict + (size_t)c * K * E;

    // ---- stage dict slice + per-code squared norms (verified fma order)
#pragma unroll
    for (int rep = 0; rep < 4; ++rep) {
        const int k = tid + rep * 128;
        const float4* p = reinterpret_cast<const float4*>(dbase + k * E);
        const float4 d0 = p[0], d1 = p[1], d2 = p[2], d3 = p[3];
        float s = d0.x * d0.x;
        s = fmaf(d0.y, d0.y, s); s = fmaf(d0.z, d0.z, s); s = fmaf(d0.w, d0.w, s);
        s = fmaf(d1.x, d1.x, s); s = fmaf(d1.y, d1.y, s);
        s = fmaf(d1.z, d1.z, s); s = fmaf(d1.w, d1.w, s);
        s = fmaf(d2.x, d2.x, s); s = fmaf(d2.y, d2.y, s);
        s = fmaf(d2.z, d2.z, s); s = fmaf(d2.w, d2.w, s);
        s = fmaf(d3.x, d3.x, s); s = fmaf(d3.y, d3.y, s);
        s = fmaf(d3.z, d3.z, s); s = fmaf(d3.w, d3.w, s);
        float4* q4 = reinterpret_cast<float4*>(&dict_s[k * E]);
        q4[0] = d0; q4[1] = d1; q4[2] = d2; q4[3] = d3;
        nrm_s[k] = s;
    }
    if (tid < 4)   // zero the pad row (read by the pipeline, never computed)
        reinterpret_cast<float4*>(&dict_s[K * E])[tid] =
            make_float4(0.f, 0.f, 0.f, 0.f);
    if (tid == 4) nrm_s[K] = 0.f;
    __syncthreads();

    // ---- this lane's R query rows: row = tid + 128*s  (covers B=512)
    float4 m[R][4];
    float  nm[R];
#pragma unroll
    for (int s = 0; s < R; ++s) {
        const int b = tid + 128 * s;
        const float4* p = reinterpret_cast<const float4*>(
            mu + (size_t)b * MUS + c * E);
        m[s][0] = p[0]; m[s][1] = p[1]; m[s][2] = p[2]; m[s][3] = p[3];
        float v = m[s][0].x * m[s][0].x;
        v = fmaf(m[s][0].y, m[s][0].y, v);
        v = fmaf(m[s][0].z, m[s][0].z, v);
        v = fmaf(m[s][0].w, m[s][0].w, v);
#pragma unroll
        for (int t = 1; t < 4; ++t) {
            v = fmaf(m[s][t].x, m[s][t].x, v);
            v = fmaf(m[s][t].y, m[s][t].y, v);
            v = fmaf(m[s][t].z, m[s][t].z, v);
            v = fmaf(m[s][t].w, m[s][t].w, v);
        }
        nm[s] = v;
    }

    // ---- serial scan, 2-stage software pipeline on the dict broadcast.
    float bd[R], sec[R];
    int   bk[R];
#pragma unroll
    for (int s = 0; s < R; ++s) { bd[s] = FLT_MAX; sec[s] = FLT_MAX; bk[s] = K; }

    const float4* __restrict__ ds4 = reinterpret_cast<const float4*>(dict_s);

    // per-k update, identical fma order / rounding to verified v7
#define VQ_COMPUTE(D0, D1, D2, D3, NR, KK)                                   \
    _Pragma("unroll")                                                        \
    for (int s = 0; s < R; ++s) {                                            \
        float acc = (D0).x * m[s][0].x;                                      \
        acc = fmaf((D0).y, m[s][0].y, acc);                                  \
        acc = fmaf((D0).z, m[s][0].z, acc);                                  \
        acc = fmaf((D0).w, m[s][0].w, acc);                                  \
        acc = fmaf((D1).x, m[s][1].x, acc);                                  \
        acc = fmaf((D1).y, m[s][1].y, acc);                                  \
        acc = fmaf((D1).z, m[s][1].z, acc);                                  \
        acc = fmaf((D1).w, m[s][1].w, acc);                                  \
        acc = fmaf((D2).x, m[s][2].x, acc);                                  \
        acc = fmaf((D2).y, m[s][2].y, acc);                                  \
        acc = fmaf((D2).z, m[s][2].z, acc);                                  \
        acc = fmaf((D2).w, m[s][2].w, acc);                                  \
        acc = fmaf((D3).x, m[s][3].x, acc);                                  \
        acc = fmaf((D3).y, m[s][3].y, acc);                                  \
        acc = fmaf((D3).z, m[s][3].z, acc);                                  \
        acc = fmaf((D3).w, m[s][3].w, acc);                                  \
        const float dist = fmaf(-2.0f, acc, nm[s] + (NR));                   \
        const bool  lt   = dist < bd[s];                                     \
        sec[s] = lt ? bd[s] : fminf(sec[s], dist);                           \
        bd[s]  = lt ? dist : bd[s];                                          \
        bk[s]  = lt ? (KK) : bk[s];                                          \
    }

    // prologue: buffer A <- k=0
    float4 a0 = ds4[0], a1 = ds4[1], a2 = ds4[2], a3 = ds4[3];
    float  an = nrm_s[0];

    for (int k = 0; k < K; k += 2) {
        // issue k+1 into B, then compute k from A (FMAs hide the LDS latency)
        float4 b0 = ds4[(k + 1) * 4 + 0];
        float4 b1 = ds4[(k + 1) * 4 + 1];
        float4 b2 = ds4[(k + 1) * 4 + 2];
        float4 b3 = ds4[(k + 1) * 4 + 3];
        float  bn = nrm_s[k + 1];
        VQ_COMPUTE(a0, a1, a2, a3, an, k)

        // issue k+2 into A (pad row at k=510 -> row 512, never computed)
        a0 = ds4[(k + 2) * 4 + 0];
        a1 = ds4[(k + 2) * 4 + 1];
        a2 = ds4[(k + 2) * 4 + 2];
        a3 = ds4[(k + 2) * 4 + 3];
        an = nrm_s[k + 2];
        VQ_COMPUTE(b0, b1, b2, b3, bn, k + 1)
    }
#undef VQ_COMPUTE

    // ---- rare near-tie path: wave-cooperative fp64 re-scan per flagged row.
#pragma unroll
    for (int s = 0; s < R; ++s) {
        unsigned long long trig = __ballot(sec[s] < bd[s] + 1e-3f);
        while (trig) {
            const int r = __ffsll(trig) - 1;
            trig &= trig - 1;
            const int row = (wave << 6) + r + 128 * s;
            const float* __restrict__ qrow = mu + (size_t)row * MUS + c * E;

            double nmuD = 0.0;
#pragma unroll
            for (int t = 0; t < E; ++t) {
                const double mt = (double)qrow[t];
                nmuD += mt * mt;
            }
            double bD = DBL_MAX;
            int    bK = K;
#pragma unroll
            for (int i = 0; i < 8; ++i) {
                const int kk = lane + 64 * i;
                const float* dk = &dict_s[kk * E];
                double nd = 0.0, dt = 0.0;
#pragma unroll
                for (int t = 0; t < 4; ++t) {
                    const double dx = dk[4 * t + 0], dy = dk[4 * t + 1];
                    const double dz = dk[4 * t + 2], dw = dk[4 * t + 3];
                    const double mx = qrow[4 * t + 0], my = qrow[4 * t + 1];
                    const double mz = qrow[4 * t + 2], mw = qrow[4 * t + 3];
                    nd += dx * dx + dy * dy + dz * dz + dw * dw;
                    dt += dx * mx + dy * my + dz * mz + dw * mw;
                }
                const double dist = nmuD + nd - 2.0 * dt;
                if (dist < bD) { bD = dist; bK = kk; }
            }
#pragma unroll
            for (int off = 32; off; off >>= 1) {
                const double od = __shfl_down(bD, off);
                const int    ok = __shfl_down(bK, off);
                if (od < bD || (od == bD && ok < bK)) { bD = od; bK = ok; }
            }
            const int kwin = __shfl(bK, 0);
            if (lane == r) bk[s] = kwin;
        }
    }

    // ---- outputs per slot: idx (coalesced), z/zq from registers.
#pragma unroll
    for (int s = 0; s < R; ++s) {
        const int b = tid + 128 * s;
        idx_t[c * B + b] = bk[s];

        const float4* dwin = reinterpret_cast<const float4*>(&dict_s[bk[s] * E]);
        const float4 q0 = dwin[0], q1 = dwin[1], q2 = dwin[2], q3 = dwin[3];
        float* zqp = zq + (size_t)b * MUS + (size_t)c * E;
        float* zp  = z  + (size_t)b * MUS + (size_t)c * E;
        reinterpret_cast<float4*>(zqp)[0] = q0;
        reinterpret_cast<float4*>(zqp)[1] = q1;
        reinterpret_cast<float4*>(zqp)[2] = q2;
        reinterpret_cast<float4*>(zqp)[3] = q3;
        float4 z0, z1, z2, z3;
        z0.x = m[s][0].x + (q0.x - m[s][0].x); z0.y = m[s][0].y + (q0.y - m[s][0].y);
        z0.z = m[s][0].z + (q0.z - m[s][0].z); z0.w = m[s][0].w + (q0.w - m[s][0].w);
        z1.x = m[s][1].x + (q1.x - m[s][1].x); z1.y = m[s][1].y + (q1.y - m[s][1].y);
        z1.z = m[s][1].z + (q1.z - m[s][1].z); z1.w = m[s][1].w + (q1.w - m[s][1].w);
        z2.x = m[s][2].x + (q2.x - m[s][2].x); z2.y = m[s][2].y + (q2.y - m[s][2].y);
        z2.z = m[s][2].z + (q2.z - m[s][2].z); z2.w = m[s][2].w + (q2.w - m[s][2].w);
        z3.x = m[s][3].x + (q3.x - m[s][3].x); z3.y = m[s][3].y + (q3.y - m[s][3].y);
        z3.z = m[s][3].z + (q3.z - m[s][3].z); z3.w = m[s][3].w + (q3.w - m[s][3].w);
        reinterpret_cast<float4*>(zp)[0] = z0;
        reinterpret_cast<float4*>(zp)[1] = z1;
        reinterpret_cast<float4*>(zp)[2] = z2;
        reinterpret_cast<float4*>(zp)[3] = z3;
    }
}

// ============================================================================
// Kernel 2 — one-hot writer: perfectly linear grid-stride float4 nt-stores
// over the 512 MB oh buffer (fill-kernel pattern). Row index is wave-uniform
// -> readfirstlane + scalar idx lookup (idx_t is 1 MB, L2-hot).
// (byte-identical to the 669.8us v7 configuration)
// ============================================================================
__launch_bounds__(256)
__global__ void vq_onehot(const int* __restrict__ idx_t,
                          float* __restrict__ oh)
{
    const long TOT = (long)B * C * K / 4;            // 33,554,432 float4s
    const long stride = (long)gridDim.x * blockDim.x;
    long f4 = (long)blockIdx.x * blockDim.x + threadIdx.x;
#pragma unroll 4
    for (; f4 < TOT; f4 += stride) {
        const int rowu = __builtin_amdgcn_readfirstlane((int)(f4 >> 7));
        const int bb   = rowu >> 9;                  // / C
        const int cc   = rowu & (C - 1);
        const int kk   = idx_t[cc * B + bb];         // scalar load, L2-hot
        const int k0   = ((int)f4 & 127) << 2;
        f32x4 v;
        v.x = (k0 + 0 == kk) ? 1.0f : 0.0f;
        v.y = (k0 + 1 == kk) ? 1.0f : 0.0f;
        v.z = (k0 + 2 == kk) ? 1.0f : 0.0f;
        v.w = (k0 + 3 == kk) ? 1.0f : 0.0f;
        __builtin_nontemporal_store(v, reinterpret_cast<f32x4*>(oh) + f4);
    }
}

extern "C" void kernel_launch(void* const* d_in, const int* in_sizes, int n_in,
                              void* d_out, int out_size, void* d_ws, size_t ws_size,
                              hipStream_t stream)
{
    const float* mu   = (const float*)d_in[0];
    const float* dict = (const float*)d_in[1];

    float* z  = (float*)d_out;                 // (B, C*E)
    float* zq = z  + (size_t)B * C * E;        // (B, C*E)
    float* oh = zq + (size_t)B * C * E;        // (B, C, K)

    int* idx_t = (int*)d_ws;                   // C*B*4 = 1 MB workspace

    vq_scan<<<dim3(C), 128, 0, stream>>>(mu, dict, z, zq, idx_t);
    vq_onehot<<<2048, 256, 0, stream>>>(idx_t, oh);
}